// Round 3
// baseline (1870.944 us; speedup 1.0000x reference)
//
#include <hip/hip_runtime.h>
#include <hip/hip_bf16.h>
#include <stdint.h>

#define NROWS 8192      // B*L = 4*2048
#define BATCH 4
#define DM    1024
#define DI    2048
#define DSTATE 16
#define DTRANK 64

typedef __attribute__((ext_vector_type(8))) __bf16 bf16x8;
typedef __attribute__((ext_vector_type(4))) float f32x4;
typedef __attribute__((ext_vector_type(8))) unsigned short u16x8;

__device__ inline float b2f(unsigned short u) {
    union { unsigned int i; float f; } v; v.i = ((unsigned int)u) << 16; return v.f;
}
__device__ inline unsigned short f2b(float f) {
    union { float f; unsigned int i; } v; v.f = f;
    unsigned int r = v.i + 0x7FFF + ((v.i >> 16) & 1);
    return (unsigned short)(r >> 16);
}

__device__ inline void gload16(const void* g, void* l) {
    __builtin_amdgcn_global_load_lds(
        (const __attribute__((address_space(1))) unsigned int*)g,
        (__attribute__((address_space(3))) unsigned int*)l, 16, 0, 0);
}

// ---------- converts ----------
__global__ __launch_bounds__(256) void cvt_bf16_k(const float* __restrict__ src,
                                                  unsigned short* __restrict__ dst,
                                                  int n4) {
    int i = blockIdx.x * 256 + threadIdx.x;
    if (i >= n4) return;
    float4 v = ((const float4*)src)[i];
    ushort4 o;
    o.x = f2b(v.x); o.y = f2b(v.y); o.z = f2b(v.z); o.w = f2b(v.w);
    ((ushort4*)dst)[i] = o;
}

__global__ __launch_bounds__(256) void pad_xproj_k(const float* __restrict__ src,
                                                   unsigned short* __restrict__ dst) {
    int i = blockIdx.x * 256 + threadIdx.x;   // over 128*2048
    int r = i >> 11, c = i & 2047;
    dst[i] = (r < 96) ? f2b(src[r * 2048 + c]) : (unsigned short)0;
}

__global__ __launch_bounds__(256) void cvt_dt_k(const float* __restrict__ xdbl,
                                                unsigned short* __restrict__ dt) {
    int i = blockIdx.x * 256 + threadIdx.x;   // over 8192*64
    int r = i >> 6, c = i & 63;
    dt[i] = f2b(xdbl[r * 128 + c]);
}

// ---------- GEMM: C[M,N] = A[M,K] @ Bw[N,K]^T  (bf16 in, f32 acc) ----------
// EPI: 0 = store bf16, 1 = store f32, 2 = softplus(acc + bias[col]) -> f32
template<int EPI>
__global__ __launch_bounds__(256) void gemm_nt(const unsigned short* __restrict__ A,
                                               const unsigned short* __restrict__ Bw,
                                               void* __restrict__ Cp,
                                               const float* __restrict__ bias,
                                               int M, int N, int K) {
    __shared__ unsigned short As[128][32];
    __shared__ unsigned short Bs[128][32];
    const int t = threadIdx.x;
    const int l = t & 63;
    const int w = t >> 6;
    const int wr = w >> 1, wc = w & 1;
    const int row0 = blockIdx.x * 128, col0 = blockIdx.y * 128;
    const int sr = t >> 2;
    const int sc = (t & 3) * 8;
    const int lr = l & 15, lk = (l >> 4) * 8;

    f32x4 acc[4][4];
#pragma unroll
    for (int m = 0; m < 4; m++)
#pragma unroll
        for (int n = 0; n < 4; n++) acc[m][n] = (f32x4){0.f, 0.f, 0.f, 0.f};

    for (int kt = 0; kt < K; kt += 32) {
        gload16(A + (size_t)(row0 + sr) * K + kt + sc, &As[sr][sc]);
        gload16(A + (size_t)(row0 + sr + 64) * K + kt + sc, &As[sr + 64][sc]);
        gload16(Bw + (size_t)(col0 + sr) * K + kt + sc, &Bs[sr][sc]);
        gload16(Bw + (size_t)(col0 + sr + 64) * K + kt + sc, &Bs[sr + 64][sc]);
        __syncthreads();   // compiler drains vmcnt before barrier -> LDS ready
        bf16x8 af[4], bfr[4];
#pragma unroll
        for (int m = 0; m < 4; m++)
            af[m] = *(const bf16x8*)&As[wr * 64 + m * 16 + lr][lk];
#pragma unroll
        for (int n = 0; n < 4; n++)
            bfr[n] = *(const bf16x8*)&Bs[wc * 64 + n * 16 + lr][lk];
#pragma unroll
        for (int m = 0; m < 4; m++)
#pragma unroll
            for (int n = 0; n < 4; n++)
                acc[m][n] = __builtin_amdgcn_mfma_f32_16x16x32_bf16(af[m], bfr[n], acc[m][n], 0, 0, 0);
        __syncthreads();   // LDS reads done before next stage overwrites
    }

    // epilogue: C/D layout col=lane&15, row=(lane>>4)*4+i  [m89-verified]
    const int er = (l >> 4) * 4;
    const int ec = l & 15;
#pragma unroll
    for (int m = 0; m < 4; m++) {
#pragma unroll
        for (int n = 0; n < 4; n++) {
            const int gcol = col0 + wc * 64 + n * 16 + ec;
#pragma unroll
            for (int i = 0; i < 4; i++) {
                const int grow = row0 + wr * 64 + m * 16 + er + i;
                float v = acc[m][n][i];
                if (EPI == 0) {
                    ((unsigned short*)Cp)[(size_t)grow * N + gcol] = f2b(v);
                } else if (EPI == 1) {
                    ((float*)Cp)[(size_t)grow * N + gcol] = v;
                } else {
                    float xx = v + bias[gcol];
                    float sp = (xx > 15.f) ? xx : log1pf(__expf(xx));
                    ((float*)Cp)[(size_t)grow * N + gcol] = sp;
                }
            }
        }
    }
}

// ---------- causal depthwise conv (k=4) + SiLU, bf16 in/out ----------
__global__ __launch_bounds__(256) void conv_silu_k(const unsigned short* __restrict__ xz, // [8192][4096]
                                                   const float* __restrict__ cw,          // [2048][4]
                                                   const float* __restrict__ cb,
                                                   unsigned short* __restrict__ xact) {   // [8192][2048]
    const int t = threadIdx.x;
    const int row = blockIdx.x;        // b*2048 + l
    const int l = row & 2047;
    const int d8 = t * 8;

    float acc[8];
    float wgt[8][4];
#pragma unroll
    for (int i = 0; i < 8; i++) {
        float4 wv = *(const float4*)&cw[(d8 + i) * 4];
        wgt[i][0] = wv.x; wgt[i][1] = wv.y; wgt[i][2] = wv.z; wgt[i][3] = wv.w;
        acc[i] = cb[d8 + i];
    }
#pragma unroll
    for (int j = 0; j < 4; j++) {
        const int ls = l - 3 + j;
        if (ls < 0) continue;
        u16x8 v = *(const u16x8*)(xz + (size_t)(row - 3 + j) * 4096 + d8);
#pragma unroll
        for (int i = 0; i < 8; i++) acc[i] = fmaf(wgt[i][j], b2f(v[i]), acc[i]);
    }
    u16x8 o;
#pragma unroll
    for (int i = 0; i < 8; i++) {
        float xx = acc[i];
        o[i] = f2b(xx / (1.f + __expf(-xx)));
    }
    *(u16x8*)(xact + (size_t)row * 2048 + d8) = o;
}

// ---------- selective scan + skip + gating, fused ----------
// 16 lanes per (b,d) channel; lane n owns state n. 512 blocks x 256 threads.
__global__ __launch_bounds__(256) void scan_k(const float* __restrict__ delta,          // [8192][2048]
                                              const unsigned short* __restrict__ xact, // [8192][2048] bf16 (u)
                                              const float* __restrict__ xdbl,          // [8192][128]: B at +64, C at +80
                                              const unsigned short* __restrict__ xz,   // [8192][4096]: z at 2048+d
                                              const float* __restrict__ A_log,         // [2048][16]
                                              const float* __restrict__ Dv,            // [2048]
                                              unsigned short* __restrict__ y) {        // [8192][2048] bf16
    const int t = threadIdx.x;
    const int g = t >> 4, n = t & 15;
    const int b = blockIdx.x >> 7;                  // 128 blocks per batch
    const int d = ((blockIdx.x & 127) << 4) + g;
    const float Aln2 = -__expf(A_log[d * 16 + n]) * 1.44269504089f;
    const float Dd = Dv[d];
    float h = 0.f;
    const size_t base = (size_t)b * 2048;

    for (int ll = 0; ll < 2048; ++ll) {
        const size_t r = base + ll;
        const float dl = delta[r * 2048 + d];
        const float u = b2f(xact[r * 2048 + d]);
        const float Bn = xdbl[r * 128 + 64 + n];
        const float Cn = xdbl[r * 128 + 80 + n];
        const float dA = __builtin_amdgcn_exp2f(dl * Aln2);   // exp(dl*A)
        h = fmaf(h, dA, dl * u * Bn);
        float v = h * Cn;
        v += __shfl_xor(v, 8, 64);
        v += __shfl_xor(v, 4, 64);
        v += __shfl_xor(v, 2, 64);
        v += __shfl_xor(v, 1, 64);
        if (n == 0) {
            const float z = b2f(xz[r * 4096 + 2048 + d]);
            const float sz = z / (1.f + __expf(-z));
            y[r * 2048 + d] = f2b((v + Dd * u) * sz);
        }
    }
}

extern "C" void kernel_launch(void* const* d_in, const int* in_sizes, int n_in,
                              void* d_out, int out_size, void* d_ws, size_t ws_size,
                              hipStream_t stream) {
    const float* x         = (const float*)d_in[0];
    const float* in_proj_w = (const float*)d_in[1];
    const float* conv_w    = (const float*)d_in[2];
    const float* conv_b    = (const float*)d_in[3];
    const float* x_proj_w  = (const float*)d_in[4];
    const float* dt_proj_w = (const float*)d_in[5];
    const float* dt_proj_b = (const float*)d_in[6];
    const float* A_log     = (const float*)d_in[7];
    const float* Dv        = (const float*)d_in[8];
    const float* out_proj_w= (const float*)d_in[9];
    float* out = (float*)d_out;

    char* p = (char*)d_ws;
    auto alloc = [&](size_t n) { char* r = p; p += (n + 255) & ~255ULL; return r; };
    unsigned short* xb   = (unsigned short*)alloc((size_t)NROWS * DM * 2);       // x bf16
    unsigned short* win  = (unsigned short*)alloc((size_t)4096 * DM * 2);        // in_proj bf16
    unsigned short* wxp  = (unsigned short*)alloc((size_t)128 * DI * 2);         // x_proj padded bf16
    unsigned short* wdt  = (unsigned short*)alloc((size_t)DI * DTRANK * 2);      // dt_proj bf16
    unsigned short* wout = (unsigned short*)alloc((size_t)DM * DI * 2);          // out_proj bf16
    unsigned short* xzb  = (unsigned short*)alloc((size_t)NROWS * 4096 * 2);     // xz bf16
    unsigned short* xab  = (unsigned short*)alloc((size_t)NROWS * DI * 2);       // xact bf16
    float*          xdbl = (float*)alloc((size_t)NROWS * 128 * 4);               // x_dbl f32
    unsigned short* dtb  = (unsigned short*)alloc((size_t)NROWS * DTRANK * 2);   // dt bf16
    float*          dlt  = (float*)alloc((size_t)NROWS * DI * 4);                // delta f32
    unsigned short* yb   = (unsigned short*)alloc((size_t)NROWS * DI * 2);       // y bf16

    // converts
    cvt_bf16_k<<<(NROWS * DM / 4 + 255) / 256, 256, 0, stream>>>(x, xb, NROWS * DM / 4);
    cvt_bf16_k<<<(4096 * DM / 4 + 255) / 256, 256, 0, stream>>>(in_proj_w, win, 4096 * DM / 4);
    cvt_bf16_k<<<(DI * DTRANK / 4 + 255) / 256, 256, 0, stream>>>(dt_proj_w, wdt, DI * DTRANK / 4);
    cvt_bf16_k<<<(DM * DI / 4 + 255) / 256, 256, 0, stream>>>(out_proj_w, wout, DM * DI / 4);
    pad_xproj_k<<<(128 * DI) / 256, 256, 0, stream>>>(x_proj_w, wxp);

    // 1) xz = x @ in_proj^T   [8192,4096]
    gemm_nt<0><<<dim3(NROWS / 128, 4096 / 128), 256, 0, stream>>>(xb, win, xzb, nullptr, NROWS, 4096, DM);
    // 2) conv + silu -> xact
    conv_silu_k<<<NROWS, 256, 0, stream>>>(xzb, conv_w, conv_b, xab);
    // 3) x_dbl = xact @ x_proj^T (padded N=128)
    gemm_nt<1><<<dim3(NROWS / 128, 1), 256, 0, stream>>>(xab, wxp, xdbl, nullptr, NROWS, 128, DI);
    // 4) dt slice -> bf16
    cvt_dt_k<<<(NROWS * DTRANK) / 256, 256, 0, stream>>>(xdbl, dtb);
    // 5) delta = softplus(dt @ dt_proj^T + b)  [8192,2048] f32
    gemm_nt<2><<<dim3(NROWS / 128, DI / 128), 256, 0, stream>>>(dtb, wdt, dlt, dt_proj_b, NROWS, DI, DTRANK);
    // 6) selective scan + D*u skip + silu(z) gate -> y bf16  (512 blocks)
    scan_k<<<(BATCH * DI * 16) / 256, 256, 0, stream>>>(dlt, xab, xdbl, xzb, A_log, Dv, yb);
    // 7) out = y @ out_proj^T  [8192,1024] f32
    gemm_nt<1><<<dim3(NROWS / 128, DM / 128), 256, 0, stream>>>(yb, wout, out, nullptr, NROWS, DM, DI);
}

// Round 7
// 772.306 us; speedup vs baseline: 2.4225x; 2.4225x over previous
//
#include <hip/hip_runtime.h>
#include <hip/hip_bf16.h>
#include <stdint.h>

#define NROWS 8192      // B*L = 4*2048
#define BATCH 4
#define DM    1024
#define DI    2048
#define DSTATE 16
#define DTRANK 64
#define CL    64        // scan chunk length
#define NCH   32        // 2048 / CL

typedef __attribute__((ext_vector_type(8))) __bf16 bf16x8;
typedef __attribute__((ext_vector_type(4))) float f32x4;
typedef __attribute__((ext_vector_type(8))) unsigned short u16x8;

__device__ inline float b2f(unsigned short u) {
    union { unsigned int i; float f; } v; v.i = ((unsigned int)u) << 16; return v.f;
}
__device__ inline unsigned short f2b(float f) {
    union { float f; unsigned int i; } v; v.f = f;
    unsigned int r = v.i + 0x7FFF + ((v.i >> 16) & 1);
    return (unsigned short)(r >> 16);
}

__device__ inline void gload16(const void* g, void* l) {
    __builtin_amdgcn_global_load_lds(
        (const __attribute__((address_space(1))) unsigned int*)g,
        (__attribute__((address_space(3))) unsigned int*)l, 16, 0, 0);
}

// ---------- converts ----------
__global__ __launch_bounds__(256) void cvt_bf16_k(const float* __restrict__ src,
                                                  unsigned short* __restrict__ dst,
                                                  int n4) {
    int i = blockIdx.x * 256 + threadIdx.x;
    if (i >= n4) return;
    float4 v = ((const float4*)src)[i];
    ushort4 o;
    o.x = f2b(v.x); o.y = f2b(v.y); o.z = f2b(v.z); o.w = f2b(v.w);
    ((ushort4*)dst)[i] = o;
}

__global__ __launch_bounds__(256) void pad_xproj_k(const float* __restrict__ src,
                                                   unsigned short* __restrict__ dst) {
    int i = blockIdx.x * 256 + threadIdx.x;   // over 128*2048
    int r = i >> 11, c = i & 2047;
    dst[i] = (r < 96) ? f2b(src[r * 2048 + c]) : (unsigned short)0;
}

__global__ __launch_bounds__(256) void cvt_dt_k(const float* __restrict__ xdbl,
                                                unsigned short* __restrict__ dt) {
    int i = blockIdx.x * 256 + threadIdx.x;   // over 8192*64
    int r = i >> 6, c = i & 63;
    dt[i] = f2b(xdbl[r * 128 + c]);
}

// ---------- GEMM: C[M,N] = A[M,K] @ Bw[N,K]^T  (bf16 in, f32 acc) ----------
// EPI: 0 = store bf16, 1 = store f32, 2 = softplus(acc + bias[col]) -> f32
template<int EPI>
__global__ __launch_bounds__(256) void gemm_nt(const unsigned short* __restrict__ A,
                                               const unsigned short* __restrict__ Bw,
                                               void* __restrict__ Cp,
                                               const float* __restrict__ bias,
                                               int M, int N, int K) {
    __shared__ unsigned short As[128][32];
    __shared__ unsigned short Bs[128][32];
    const int t = threadIdx.x;
    const int l = t & 63;
    const int w = t >> 6;
    const int wr = w >> 1, wc = w & 1;
    const int row0 = blockIdx.x * 128, col0 = blockIdx.y * 128;
    const int sr = t >> 2;
    const int sc = (t & 3) * 8;
    const int lr = l & 15, lk = (l >> 4) * 8;

    f32x4 acc[4][4];
#pragma unroll
    for (int m = 0; m < 4; m++)
#pragma unroll
        for (int n = 0; n < 4; n++) acc[m][n] = (f32x4){0.f, 0.f, 0.f, 0.f};

    for (int kt = 0; kt < K; kt += 32) {
        gload16(A + (size_t)(row0 + sr) * K + kt + sc, &As[sr][sc]);
        gload16(A + (size_t)(row0 + sr + 64) * K + kt + sc, &As[sr + 64][sc]);
        gload16(Bw + (size_t)(col0 + sr) * K + kt + sc, &Bs[sr][sc]);
        gload16(Bw + (size_t)(col0 + sr + 64) * K + kt + sc, &Bs[sr + 64][sc]);
        __syncthreads();
        bf16x8 af[4], bfr[4];
#pragma unroll
        for (int m = 0; m < 4; m++)
            af[m] = *(const bf16x8*)&As[wr * 64 + m * 16 + lr][lk];
#pragma unroll
        for (int n = 0; n < 4; n++)
            bfr[n] = *(const bf16x8*)&Bs[wc * 64 + n * 16 + lr][lk];
#pragma unroll
        for (int m = 0; m < 4; m++)
#pragma unroll
            for (int n = 0; n < 4; n++)
                acc[m][n] = __builtin_amdgcn_mfma_f32_16x16x32_bf16(af[m], bfr[n], acc[m][n], 0, 0, 0);
        __syncthreads();
    }

    // epilogue: C/D layout col=lane&15, row=(lane>>4)*4+i  [m89-verified]
    const int er = (l >> 4) * 4;
    const int ec = l & 15;
#pragma unroll
    for (int m = 0; m < 4; m++) {
#pragma unroll
        for (int n = 0; n < 4; n++) {
            const int gcol = col0 + wc * 64 + n * 16 + ec;
#pragma unroll
            for (int i = 0; i < 4; i++) {
                const int grow = row0 + wr * 64 + m * 16 + er + i;
                float v = acc[m][n][i];
                if (EPI == 0) {
                    ((unsigned short*)Cp)[(size_t)grow * N + gcol] = f2b(v);
                } else if (EPI == 1) {
                    ((float*)Cp)[(size_t)grow * N + gcol] = v;
                } else {
                    float xx = v + bias[gcol];
                    float sp = (xx > 15.f) ? xx : log1pf(__expf(xx));
                    ((float*)Cp)[(size_t)grow * N + gcol] = sp;
                }
            }
        }
    }
}

// ---------- causal depthwise conv (k=4) + SiLU, bf16 in/out ----------
__global__ __launch_bounds__(256) void conv_silu_k(const unsigned short* __restrict__ xz, // [8192][4096]
                                                   const float* __restrict__ cw,          // [2048][4]
                                                   const float* __restrict__ cb,
                                                   unsigned short* __restrict__ xact) {   // [8192][2048]
    const int t = threadIdx.x;
    const int row = blockIdx.x;        // b*2048 + l
    const int l = row & 2047;
    const int d8 = t * 8;

    float acc[8];
    float wgt[8][4];
#pragma unroll
    for (int i = 0; i < 8; i++) {
        float4 wv = *(const float4*)&cw[(d8 + i) * 4];
        wgt[i][0] = wv.x; wgt[i][1] = wv.y; wgt[i][2] = wv.z; wgt[i][3] = wv.w;
        acc[i] = cb[d8 + i];
    }
#pragma unroll
    for (int j = 0; j < 4; j++) {
        const int ls = l - 3 + j;
        if (ls < 0) continue;
        u16x8 v = *(const u16x8*)(xz + (size_t)(row - 3 + j) * 4096 + d8);
#pragma unroll
        for (int i = 0; i < 8; i++) acc[i] = fmaf(wgt[i][j], b2f(v[i]), acc[i]);
    }
    u16x8 o;
#pragma unroll
    for (int i = 0; i < 8; i++) {
        float xx = acc[i];
        o[i] = f2b(xx / (1.f + __expf(-xx)));
    }
    *(u16x8*)(xact + (size_t)row * 2048 + d8) = o;
}

// ---------- selective scan v2: LDS-staged, double-buffered chunks ----------
// Block: 256 thr = 16 d-channels x 16 states. Grid: BATCH * DI/16 = 512.
__global__ __launch_bounds__(256) void scan_k(const float* __restrict__ dlt,           // [8192][2048] f32 delta
                                              const unsigned short* __restrict__ xact, // [8192][2048] bf16 (u)
                                              const float* __restrict__ xdbl,          // [8192][128]: B at +64, C at +80
                                              const unsigned short* __restrict__ xz,   // [8192][4096]: z at 2048+d
                                              const float* __restrict__ A_log,         // [2048][16]
                                              const float* __restrict__ Dv,            // [2048]
                                              unsigned short* __restrict__ y) {        // [8192][2048] bf16
    __shared__ float          dl_s[2][CL][16];   // 2 x 4 KB
    __shared__ unsigned short u_s [2][CL][16];   // 2 x 2 KB
    __shared__ float          BC_s[2][CL][32];   // 2 x 8 KB  (B | C)
    __shared__ float          y_s [CL][16];      // 4 KB

    const int t = threadIdx.x;
    const int g = t >> 4, n = t & 15;
    const int b = blockIdx.x >> 7;
    const int d0 = (blockIdx.x & 127) << 4;
    const int d = d0 + g;
    const size_t base = (size_t)b * 2048;

    const float Aln2 = -__expf(A_log[d * 16 + n]) * 1.44269504089f;
    const float Dd = Dv[d];
    float h = 0.f;

    auto stage = [&](int buf, int c) {
        const int r0 = c * CL;
        gload16(dlt + (size_t)(base + r0 + (t >> 2)) * 2048 + d0 + (t & 3) * 4,
                &dl_s[buf][t >> 2][(t & 3) * 4]);
        if (t < 128)
            gload16(xact + (size_t)(base + r0 + (t >> 1)) * 2048 + d0 + (t & 1) * 8,
                    &u_s[buf][t >> 1][(t & 1) * 8]);
        gload16(xdbl + (size_t)(base + r0 + (t >> 3)) * 128 + 64 + (t & 7) * 4,
                &BC_s[buf][t >> 3][(t & 7) * 4]);
        gload16(xdbl + (size_t)(base + r0 + 32 + (t >> 3)) * 128 + 64 + (t & 7) * 4,
                &BC_s[buf][32 + (t >> 3)][(t & 7) * 4]);
    };

    stage(0, 0);
    __syncthreads();    // drain chunk 0

    for (int c = 0; c < NCH; ++c) {
        const int cur = c & 1;
        if (c + 1 < NCH) stage(cur ^ 1, c + 1);   // in flight during compute

        const float* dlp = &dl_s[cur][0][0];
        const unsigned short* up = &u_s[cur][0][0];
        const float* bcp = &BC_s[cur][0][0];

#pragma unroll 8
        for (int r = 0; r < CL; ++r) {
            const float dl = dlp[r * 16 + g];
            const float u  = b2f(up[r * 16 + g]);
            const float Bn = bcp[r * 32 + n];
            const float Cn = bcp[r * 32 + 16 + n];
            const float dA = __builtin_amdgcn_exp2f(dl * Aln2);
            h = fmaf(h, dA, dl * u * Bn);
            float v = h * Cn;
            v += __shfl_xor(v, 8, 64);
            v += __shfl_xor(v, 4, 64);
            v += __shfl_xor(v, 2, 64);
            v += __shfl_xor(v, 1, 64);
            if (n == 0) y_s[r][g] = v + Dd * u;
        }
        __syncthreads();   // y_s complete; next-chunk stage also drained here

        // flush: thread t -> row rr = t>>2, cols c0..c0+3; gate with silu(z)
        {
            const int rr = t >> 2, c0 = (t & 3) * 4;
            const size_t row = base + (size_t)c * CL + rr;
            float4 vv = *(const float4*)&y_s[rr][c0];
            ushort4 zz = *(const ushort4*)(xz + row * 4096 + 2048 + d0 + c0);
            ushort4 oo;
            {
                float z0 = b2f(zz.x), z1 = b2f(zz.y), z2 = b2f(zz.z), z3 = b2f(zz.w);
                oo.x = f2b(vv.x * (z0 / (1.f + __expf(-z0))));
                oo.y = f2b(vv.y * (z1 / (1.f + __expf(-z1))));
                oo.z = f2b(vv.z * (z2 / (1.f + __expf(-z2))));
                oo.w = f2b(vv.w * (z3 / (1.f + __expf(-z3))));
            }
            *(ushort4*)(y + row * 2048 + d0 + c0) = oo;
        }
        __syncthreads();   // y_s free for next chunk
    }
}

extern "C" void kernel_launch(void* const* d_in, const int* in_sizes, int n_in,
                              void* d_out, int out_size, void* d_ws, size_t ws_size,
                              hipStream_t stream) {
    const float* x         = (const float*)d_in[0];
    const float* in_proj_w = (const float*)d_in[1];
    const float* conv_w    = (const float*)d_in[2];
    const float* conv_b    = (const float*)d_in[3];
    const float* x_proj_w  = (const float*)d_in[4];
    const float* dt_proj_w = (const float*)d_in[5];
    const float* dt_proj_b = (const float*)d_in[6];
    const float* A_log     = (const float*)d_in[7];
    const float* Dv        = (const float*)d_in[8];
    const float* out_proj_w= (const float*)d_in[9];
    float* out = (float*)d_out;

    char* p = (char*)d_ws;
    auto alloc = [&](size_t n) { char* r = p; p += (n + 255) & ~255ULL; return r; };
    unsigned short* xb   = (unsigned short*)alloc((size_t)NROWS * DM * 2);       // x bf16
    unsigned short* win  = (unsigned short*)alloc((size_t)4096 * DM * 2);        // in_proj bf16
    unsigned short* wxp  = (unsigned short*)alloc((size_t)128 * DI * 2);         // x_proj padded bf16
    unsigned short* wdt  = (unsigned short*)alloc((size_t)DI * DTRANK * 2);      // dt_proj bf16
    unsigned short* wout = (unsigned short*)alloc((size_t)DM * DI * 2);          // out_proj bf16
    unsigned short* xzb  = (unsigned short*)alloc((size_t)NROWS * 4096 * 2);     // xz bf16
    unsigned short* xab  = (unsigned short*)alloc((size_t)NROWS * DI * 2);       // xact bf16
    float*          xdbl = (float*)alloc((size_t)NROWS * 128 * 4);               // x_dbl f32
    unsigned short* dtb  = (unsigned short*)alloc((size_t)NROWS * DTRANK * 2);   // dt bf16
    float*          dlt  = (float*)alloc((size_t)NROWS * DI * 4);                // delta f32
    unsigned short* yb   = (unsigned short*)alloc((size_t)NROWS * DI * 2);       // y bf16

    // converts
    cvt_bf16_k<<<(NROWS * DM / 4 + 255) / 256, 256, 0, stream>>>(x, xb, NROWS * DM / 4);
    cvt_bf16_k<<<(4096 * DM / 4 + 255) / 256, 256, 0, stream>>>(in_proj_w, win, 4096 * DM / 4);
    cvt_bf16_k<<<(DI * DTRANK / 4 + 255) / 256, 256, 0, stream>>>(dt_proj_w, wdt, DI * DTRANK / 4);
    cvt_bf16_k<<<(DM * DI / 4 + 255) / 256, 256, 0, stream>>>(out_proj_w, wout, DM * DI / 4);
    pad_xproj_k<<<(128 * DI) / 256, 256, 0, stream>>>(x_proj_w, wxp);

    // 1) xz = x @ in_proj^T   [8192,4096]
    gemm_nt<0><<<dim3(NROWS / 128, 4096 / 128), 256, 0, stream>>>(xb, win, xzb, nullptr, NROWS, 4096, DM);
    // 2) conv + silu -> xact
    conv_silu_k<<<NROWS, 256, 0, stream>>>(xzb, conv_w, conv_b, xab);
    // 3) x_dbl = xact @ x_proj^T (padded N=128)
    gemm_nt<1><<<dim3(NROWS / 128, 1), 256, 0, stream>>>(xab, wxp, xdbl, nullptr, NROWS, 128, DI);
    // 4) dt slice -> bf16
    cvt_dt_k<<<(NROWS * DTRANK) / 256, 256, 0, stream>>>(xdbl, dtb);
    // 5) delta = softplus(dt @ dt_proj^T + b)  [8192,2048] f32
    gemm_nt<2><<<dim3(NROWS / 128, DI / 128), 256, 0, stream>>>(dtb, wdt, dlt, dt_proj_b, NROWS, DI, DTRANK);
    // 6) selective scan + D*u skip + silu(z) gate -> y bf16  (512 blocks)
    scan_k<<<(BATCH * DI * 16) / 256, 256, 0, stream>>>(dlt, xab, xdbl, xzb, A_log, Dv, yb);
    // 7) out = y @ out_proj^T  [8192,1024] f32
    gemm_nt<1><<<dim3(NROWS / 128, DM / 128), 256, 0, stream>>>(yb, wout, out, nullptr, NROWS, DM, DI);
}

// Round 10
// 523.402 us; speedup vs baseline: 3.5746x; 1.4755x over previous
//
#include <hip/hip_runtime.h>
#include <hip/hip_bf16.h>
#include <stdint.h>

#define NROWS 8192      // B*L = 4*2048
#define BATCH 4
#define DM    1024
#define DI    2048
#define DSTATE 16
#define DTRANK 64
#define CL    32        // scan chunk length
#define NCH   64        // 2048 / CL

typedef __attribute__((ext_vector_type(8))) __bf16 bf16x8;
typedef __attribute__((ext_vector_type(4))) float f32x4;
typedef __attribute__((ext_vector_type(8))) unsigned short u16x8;

__device__ inline float b2f(unsigned short u) {
    union { unsigned int i; float f; } v; v.i = ((unsigned int)u) << 16; return v.f;
}
__device__ inline unsigned short f2b(float f) {
    union { float f; unsigned int i; } v; v.f = f;
    unsigned int r = v.i + 0x7FFF + ((v.i >> 16) & 1);
    return (unsigned short)(r >> 16);
}

__device__ inline void gload16(const void* g, void* l) {
    __builtin_amdgcn_global_load_lds(
        (const __attribute__((address_space(1))) unsigned int*)g,
        (__attribute__((address_space(3))) unsigned int*)l, 16, 0, 0);
}

// ---------- converts ----------
__global__ __launch_bounds__(256) void cvt_bf16_k(const float* __restrict__ src,
                                                  unsigned short* __restrict__ dst,
                                                  int n4) {
    int i = blockIdx.x * 256 + threadIdx.x;
    if (i >= n4) return;
    float4 v = ((const float4*)src)[i];
    ushort4 o;
    o.x = f2b(v.x); o.y = f2b(v.y); o.z = f2b(v.z); o.w = f2b(v.w);
    ((ushort4*)dst)[i] = o;
}

__global__ __launch_bounds__(256) void pad_xproj_k(const float* __restrict__ src,
                                                   unsigned short* __restrict__ dst) {
    int i = blockIdx.x * 256 + threadIdx.x;   // over 128*2048
    int r = i >> 11, c = i & 2047;
    dst[i] = (r < 96) ? f2b(src[r * 2048 + c]) : (unsigned short)0;
}

__global__ __launch_bounds__(256) void cvt_dt_k(const float* __restrict__ xdbl,
                                                unsigned short* __restrict__ dt) {
    int i = blockIdx.x * 256 + threadIdx.x;   // over 8192*64
    int r = i >> 6, c = i & 63;
    dt[i] = f2b(xdbl[r * 128 + c]);
}

// ---------- GEMM: C[M,N] = A[M,K] @ Bw[N,K]^T  (bf16 in, f32 acc) ----------
// EPI: 0 = store bf16, 1 = store f32, 2 = softplus(acc + bias[col]) -> f32
template<int EPI>
__global__ __launch_bounds__(256) void gemm_nt(const unsigned short* __restrict__ A,
                                               const unsigned short* __restrict__ Bw,
                                               void* __restrict__ Cp,
                                               const float* __restrict__ bias,
                                               int M, int N, int K) {
    __shared__ unsigned short As[128][32];
    __shared__ unsigned short Bs[128][32];
    const int t = threadIdx.x;
    const int l = t & 63;
    const int w = t >> 6;
    const int wr = w >> 1, wc = w & 1;
    const int row0 = blockIdx.x * 128, col0 = blockIdx.y * 128;
    const int sr = t >> 2;
    const int sc = (t & 3) * 8;
    const int lr = l & 15, lk = (l >> 4) * 8;

    f32x4 acc[4][4];
#pragma unroll
    for (int m = 0; m < 4; m++)
#pragma unroll
        for (int n = 0; n < 4; n++) acc[m][n] = (f32x4){0.f, 0.f, 0.f, 0.f};

    for (int kt = 0; kt < K; kt += 32) {
        gload16(A + (size_t)(row0 + sr) * K + kt + sc, &As[sr][sc]);
        gload16(A + (size_t)(row0 + sr + 64) * K + kt + sc, &As[sr + 64][sc]);
        gload16(Bw + (size_t)(col0 + sr) * K + kt + sc, &Bs[sr][sc]);
        gload16(Bw + (size_t)(col0 + sr + 64) * K + kt + sc, &Bs[sr + 64][sc]);
        __syncthreads();
        bf16x8 af[4], bfr[4];
#pragma unroll
        for (int m = 0; m < 4; m++)
            af[m] = *(const bf16x8*)&As[wr * 64 + m * 16 + lr][lk];
#pragma unroll
        for (int n = 0; n < 4; n++)
            bfr[n] = *(const bf16x8*)&Bs[wc * 64 + n * 16 + lr][lk];
#pragma unroll
        for (int m = 0; m < 4; m++)
#pragma unroll
            for (int n = 0; n < 4; n++)
                acc[m][n] = __builtin_amdgcn_mfma_f32_16x16x32_bf16(af[m], bfr[n], acc[m][n], 0, 0, 0);
        __syncthreads();
    }

    // epilogue: C/D layout col=lane&15, row=(lane>>4)*4+i  [m89-verified]
    const int er = (l >> 4) * 4;
    const int ec = l & 15;
#pragma unroll
    for (int m = 0; m < 4; m++) {
#pragma unroll
        for (int n = 0; n < 4; n++) {
            const int gcol = col0 + wc * 64 + n * 16 + ec;
#pragma unroll
            for (int i = 0; i < 4; i++) {
                const int grow = row0 + wr * 64 + m * 16 + er + i;
                float v = acc[m][n][i];
                if (EPI == 0) {
                    ((unsigned short*)Cp)[(size_t)grow * N + gcol] = f2b(v);
                } else if (EPI == 1) {
                    ((float*)Cp)[(size_t)grow * N + gcol] = v;
                } else {
                    float xx = v + bias[gcol];
                    float sp = (xx > 15.f) ? xx : log1pf(__expf(xx));
                    ((float*)Cp)[(size_t)grow * N + gcol] = sp;
                }
            }
        }
    }
}

// ---------- causal depthwise conv (k=4) + SiLU, bf16 in/out ----------
__global__ __launch_bounds__(256) void conv_silu_k(const unsigned short* __restrict__ xz, // [8192][4096]
                                                   const float* __restrict__ cw,          // [2048][4]
                                                   const float* __restrict__ cb,
                                                   unsigned short* __restrict__ xact) {   // [8192][2048]
    const int t = threadIdx.x;
    const int row = blockIdx.x;        // b*2048 + l
    const int l = row & 2047;
    const int d8 = t * 8;

    float acc[8];
    float wgt[8][4];
#pragma unroll
    for (int i = 0; i < 8; i++) {
        float4 wv = *(const float4*)&cw[(d8 + i) * 4];
        wgt[i][0] = wv.x; wgt[i][1] = wv.y; wgt[i][2] = wv.z; wgt[i][3] = wv.w;
        acc[i] = cb[d8 + i];
    }
#pragma unroll
    for (int j = 0; j < 4; j++) {
        const int ls = l - 3 + j;
        if (ls < 0) continue;
        u16x8 v = *(const u16x8*)(xz + (size_t)(row - 3 + j) * 4096 + d8);
#pragma unroll
        for (int i = 0; i < 8; i++) acc[i] = fmaf(wgt[i][j], b2f(v[i]), acc[i]);
    }
    u16x8 o;
#pragma unroll
    for (int i = 0; i < 8; i++) {
        float xx = acc[i];
        o[i] = f2b(xx / (1.f + __expf(-xx)));
    }
    *(u16x8*)(xact + (size_t)row * 2048 + d8) = o;
}

// ---------- selective scan v3: phase-split (no cross-lane ops) ----------
// Block: 256 thr = 16 d-channels x 16 states. Grid: 512.
// Phase A: per-thread recurrence, h*C[n] -> hc_s (no shfl -> pipelineable).
// Phase B: per-(row,channel) 16-wide LDS sum + D*u + silu(z) gate -> global.
__global__ __launch_bounds__(256) void scan_k(const float* __restrict__ dlt,           // [8192][2048] f32 delta
                                              const unsigned short* __restrict__ xact, // [8192][2048] bf16 (u)
                                              const float* __restrict__ xdbl,          // [8192][128]: B at +64, C at +80
                                              const unsigned short* __restrict__ xz,   // [8192][4096]: z at 2048+d
                                              const float* __restrict__ A_log,         // [2048][16]
                                              const float* __restrict__ Dv,            // [2048]
                                              unsigned short* __restrict__ y) {        // [8192][2048] bf16
    __shared__ float          dl_s[2][CL][16];    // 4 KB
    __shared__ unsigned short u_s [2][CL][16];    // 2 KB
    __shared__ float          BC_s[2][CL][32];    // 8 KB  (B | C)
    __shared__ float          hc_s[CL][16][17];   // 34 KB (pad 17 vs 16-way bank aliasing)

    const int t = threadIdx.x;
    const int g = t >> 4, n = t & 15;
    const int b = blockIdx.x >> 7;
    const int d0 = (blockIdx.x & 127) << 4;
    const size_t base = (size_t)b * 2048;

    const float Aln2 = -__expf(A_log[(d0 + g) * 16 + n]) * 1.44269504089f;
    float h = 0.f;

    // phase-B fixed assignment: row rB, channel pair (chB, chB+1)
    const int rB = t >> 3, chB = (t & 7) * 2;
    const float D0 = Dv[d0 + chB], D1 = Dv[d0 + chB + 1];

    auto stage = [&](int buf, int c) {
        const int r0 = c * CL;
        // dl: 32 rows x 64 B -> 128 loads (waves 0,1)
        if (t < 128) {
            gload16(dlt + (size_t)(base + r0 + (t >> 2)) * 2048 + d0 + (t & 3) * 4,
                    &dl_s[buf][t >> 2][(t & 3) * 4]);
        } else if (t < 192) {
            // u: 32 rows x 32 B -> 64 loads (wave 2)
            const int i = t - 128;
            gload16(xact + (size_t)(base + r0 + (i >> 1)) * 2048 + d0 + (i & 1) * 8,
                    &u_s[buf][i >> 1][(i & 1) * 8]);
        }
        // BC: 32 rows x 128 B -> 256 loads (all waves)
        gload16(xdbl + (size_t)(base + r0 + (t >> 3)) * 128 + 64 + (t & 7) * 4,
                &BC_s[buf][t >> 3][(t & 7) * 4]);
    };

    stage(0, 0);
    __syncthreads();    // drain chunk 0

    for (int c = 0; c < NCH; ++c) {
        const int cur = c & 1;
        if (c + 1 < NCH) stage(cur ^ 1, c + 1);   // in flight during phase A

        // ---- phase A: recurrence, no cross-lane ops ----
        {
            const float* dlp = &dl_s[cur][0][0];
            const unsigned short* up = &u_s[cur][0][0];
            const float* bcp = &BC_s[cur][0][0];
#pragma unroll 8
            for (int r = 0; r < CL; ++r) {
                const float dl = dlp[r * 16 + g];
                const float u  = b2f(up[r * 16 + g]);
                const float Bn = bcp[r * 32 + n];
                const float Cn = bcp[r * 32 + 16 + n];
                const float dA = __builtin_amdgcn_exp2f(dl * Aln2);
                h = fmaf(h, dA, dl * u * Bn);
                hc_s[r][g][n] = h * Cn;
            }
        }
        __syncthreads();   // hc complete; staged chunk c+1 also drained

        // ---- phase B: reduce over states + gate + store ----
        {
            float s0 = 0.f, s1 = 0.f;
#pragma unroll
            for (int nn = 0; nn < 16; ++nn) {
                s0 += hc_s[rB][chB][nn];
                s1 += hc_s[rB][chB + 1][nn];
            }
            const float u0 = b2f(u_s[cur][rB][chB]);
            const float u1 = b2f(u_s[cur][rB][chB + 1]);
            const size_t row = base + (size_t)c * CL + rB;
            ushort2 zz = *(const ushort2*)(xz + row * 4096 + 2048 + d0 + chB);
            const float z0 = b2f(zz.x), z1 = b2f(zz.y);
            const float y0 = (s0 + D0 * u0) * (z0 / (1.f + __expf(-z0)));
            const float y1 = (s1 + D1 * u1) * (z1 / (1.f + __expf(-z1)));
            ushort2 oo; oo.x = f2b(y0); oo.y = f2b(y1);
            *(ushort2*)(y + row * 2048 + d0 + chB) = oo;
        }
        __syncthreads();   // hc + buf[cur] free for reuse
    }
}

extern "C" void kernel_launch(void* const* d_in, const int* in_sizes, int n_in,
                              void* d_out, int out_size, void* d_ws, size_t ws_size,
                              hipStream_t stream) {
    const float* x         = (const float*)d_in[0];
    const float* in_proj_w = (const float*)d_in[1];
    const float* conv_w    = (const float*)d_in[2];
    const float* conv_b    = (const float*)d_in[3];
    const float* x_proj_w  = (const float*)d_in[4];
    const float* dt_proj_w = (const float*)d_in[5];
    const float* dt_proj_b = (const float*)d_in[6];
    const float* A_log     = (const float*)d_in[7];
    const float* Dv        = (const float*)d_in[8];
    const float* out_proj_w= (const float*)d_in[9];
    float* out = (float*)d_out;

    char* p = (char*)d_ws;
    auto alloc = [&](size_t n) { char* r = p; p += (n + 255) & ~255ULL; return r; };
    unsigned short* xb   = (unsigned short*)alloc((size_t)NROWS * DM * 2);       // x bf16
    unsigned short* win  = (unsigned short*)alloc((size_t)4096 * DM * 2);        // in_proj bf16
    unsigned short* wxp  = (unsigned short*)alloc((size_t)128 * DI * 2);         // x_proj padded bf16
    unsigned short* wdt  = (unsigned short*)alloc((size_t)DI * DTRANK * 2);      // dt_proj bf16
    unsigned short* wout = (unsigned short*)alloc((size_t)DM * DI * 2);          // out_proj bf16
    unsigned short* xzb  = (unsigned short*)alloc((size_t)NROWS * 4096 * 2);     // xz bf16
    unsigned short* xab  = (unsigned short*)alloc((size_t)NROWS * DI * 2);       // xact bf16
    float*          xdbl = (float*)alloc((size_t)NROWS * 128 * 4);               // x_dbl f32
    unsigned short* dtb  = (unsigned short*)alloc((size_t)NROWS * DTRANK * 2);   // dt bf16
    float*          dlt  = (float*)alloc((size_t)NROWS * DI * 4);                // delta f32
    unsigned short* yb   = (unsigned short*)alloc((size_t)NROWS * DI * 2);       // y bf16

    // converts
    cvt_bf16_k<<<(NROWS * DM / 4 + 255) / 256, 256, 0, stream>>>(x, xb, NROWS * DM / 4);
    cvt_bf16_k<<<(4096 * DM / 4 + 255) / 256, 256, 0, stream>>>(in_proj_w, win, 4096 * DM / 4);
    cvt_bf16_k<<<(DI * DTRANK / 4 + 255) / 256, 256, 0, stream>>>(dt_proj_w, wdt, DI * DTRANK / 4);
    cvt_bf16_k<<<(DM * DI / 4 + 255) / 256, 256, 0, stream>>>(out_proj_w, wout, DM * DI / 4);
    pad_xproj_k<<<(128 * DI) / 256, 256, 0, stream>>>(x_proj_w, wxp);

    // 1) xz = x @ in_proj^T   [8192,4096]
    gemm_nt<0><<<dim3(NROWS / 128, 4096 / 128), 256, 0, stream>>>(xb, win, xzb, nullptr, NROWS, 4096, DM);
    // 2) conv + silu -> xact
    conv_silu_k<<<NROWS, 256, 0, stream>>>(xzb, conv_w, conv_b, xab);
    // 3) x_dbl = xact @ x_proj^T (padded N=128)
    gemm_nt<1><<<dim3(NROWS / 128, 1), 256, 0, stream>>>(xab, wxp, xdbl, nullptr, NROWS, 128, DI);
    // 4) dt slice -> bf16
    cvt_dt_k<<<(NROWS * DTRANK) / 256, 256, 0, stream>>>(xdbl, dtb);
    // 5) delta = softplus(dt @ dt_proj^T + b)  [8192,2048] f32
    gemm_nt<2><<<dim3(NROWS / 128, DI / 128), 256, 0, stream>>>(dtb, wdt, dlt, dt_proj_b, NROWS, DI, DTRANK);
    // 6) selective scan + D*u skip + silu(z) gate -> y bf16  (512 blocks)
    scan_k<<<(BATCH * DI * 16) / 256, 256, 0, stream>>>(dlt, xab, xdbl, xzb, A_log, Dv, yb);
    // 7) out = y @ out_proj^T  [8192,1024] f32
    gemm_nt<1><<<dim3(NROWS / 128, DM / 128), 256, 0, stream>>>(yb, wout, out, nullptr, NROWS, DM, DI);
}